// Round 12
// baseline (244.602 us; speedup 1.0000x reference)
//
#include <hip/hip_runtime.h>
#include <math.h>

#define TV 3200          // T*V = 128*25
#define NTV 204800       // N*T*V
#define NB1 512          // k_pw blocks: 64 n x 8 q (16-t tile + 2 halo slices each side)
#define NB2 400          // k_h blocks: float2 sites, 400*256 = NTV/2
#define NB3 800          // k_out blocks: (f4-site, o-quarter), 800*256 = NTV/4 * 4
constexpr float EPSF = 1e-5f;

typedef float f2 __attribute__((ext_vector_type(2)));
typedef float f4 __attribute__((ext_vector_type(4)));

// fast tanh: 1 - 2/(e^{2x}+1); exact saturation, ~1e-7 abs err in operating range
__device__ inline float fast_tanh(float x){
  float e = __expf(2.f*x);
  return 1.f - 2.f/(e + 1.f);
}

// 4-wave (256-thread) partial writer; leading sync protects lds scratch reuse
template<int NS>
__device__ inline void write_partials4(float (&vals)[NS], float* __restrict__ outp, int nb, float* lds){
  __syncthreads();
  int lane = threadIdx.x & 63, wid = threadIdx.x >> 6;
  #pragma unroll
  for (int s = 0; s < NS; ++s){
    float v = vals[s];
    #pragma unroll
    for (int o = 32; o > 0; o >>= 1) v += __shfl_down(v, o);
    if (lane == 0) lds[s*4 + wid] = v;
  }
  __syncthreads();
  if ((int)threadIdx.x < NS)
    outp[threadIdx.x*nb + blockIdx.x] = lds[threadIdx.x*4+0] + lds[threadIdx.x*4+1]
                                      + lds[threadIdx.x*4+2] + lds[threadIdx.x*4+3];
}

// 8-wave (512-thread) partial writer
template<int NS>
__device__ inline void write_partials8(float (&vals)[NS], float* __restrict__ outp, int nb, float* lds){
  __syncthreads();
  int lane = threadIdx.x & 63, wid = threadIdx.x >> 6;   // 0..7
  #pragma unroll
  for (int s = 0; s < NS; ++s){
    float v = vals[s];
    #pragma unroll
    for (int o = 32; o > 0; o >>= 1) v += __shfl_down(v, o);
    if (lane == 0) lds[s*8 + wid] = v;
  }
  __syncthreads();
  if ((int)threadIdx.x < NS){
    float t = 0.f;
    #pragma unroll
    for (int w = 0; w < 8; ++w) t += lds[threadIdx.x*8 + w];
    outp[threadIdx.x*nb + blockIdx.x] = t;
  }
}

// ==== K1: fused proj + wat. [R11-proven verbatim] ====
__global__ __launch_bounds__(512) void k_pw(
    const float* __restrict__ x,
    const float* __restrict__ Wv, const float* __restrict__ bv,
    const float* __restrict__ Wr, const float* __restrict__ br,
    const float* __restrict__ Ww, const float* __restrict__ bw,
    float* __restrict__ r0, float* __restrict__ att,
    float* __restrict__ pr, float* __restrict__ patt)
{
  __shared__ float sV[500*9];
  __shared__ float sS[500];
  __shared__ float sWvr[1024];        // [c][0..7]=Wv[r][c], [c][8..15]=Wr[r][c]
  __shared__ float sWw[125], sbw[25];
  __shared__ float red[16*8];
  const int tid = threadIdx.x;
  const int b = blockIdx.x, n = b >> 3, q = b & 7;
  const int t0 = q*16;
  for (int i2 = tid; i2 < 1024; i2 += 512){
    int c = i2 >> 4, k = i2 & 15;
    sWvr[i2] = (k < 8) ? Wv[k*64 + c] : Wr[(k-8)*64 + c];
  }
  if (tid < 125) sWw[tid] = Ww[tid];
  if (tid < 25)  sbw[tid] = bw[tid];
  __syncthreads();

  const int site = tid;                // 0..499 active
  const bool act = (site < 500);
  const bool val = act && (q > 0 || site >= 50) && (q < 7 || site < 450);
  const bool own = act && (site >= 50) && (site < 450);
  const float* xpn = x + (size_t)n*64*TV + (t0*25 - 50);
  const f4* sW4 = (const f4*)sWvr;

  float av[8]={0,0,0,0,0,0,0,0};
  float ar[8]={0,0,0,0,0,0,0,0};
  float ss = 0.f;
  if (val){
    #pragma unroll 8
    for (int c = 0; c < 64; ++c){
      float xv = __builtin_nontemporal_load(xpn + (size_t)c*TV + site);
      ss += xv;
      f4 wv0 = sW4[c*4+0], wv1 = sW4[c*4+1];
      f4 wr0 = sW4[c*4+2], wr1 = sW4[c*4+3];
      #pragma unroll
      for (int r = 0; r < 4; ++r){
        av[r]   = fmaf(wv0[r], xv, av[r]);
        av[4+r] = fmaf(wv1[r], xv, av[4+r]);
        ar[r]   = fmaf(wr0[r], xv, ar[r]);
        ar[4+r] = fmaf(wr1[r], xv, ar[4+r]);
      }
    }
  }
  if (act){
    sS[site] = ss * 0.015625f;
    #pragma unroll
    for (int r = 0; r < 8; ++r)
      sV[site*9+r] = val ? (av[r] + bv[r]) : 0.f;
  }
  const int gbase = t0*25 - 50 + site;
  float vals[16];
  {
    float rr[8];
    if (own){
      float* rp = r0 + (size_t)n*8*TV + gbase;
      #pragma unroll
      for (int r = 0; r < 8; ++r){
        rr[r] = ar[r] + br[r];
        rp[(size_t)r*TV] = rr[r];
      }
    }
    #pragma unroll
    for (int r = 0; r < 8; ++r){
      vals[r]   = own ? rr[r] : 0.f;
      vals[8+r] = own ? rr[r]*rr[r] : 0.f;
    }
  }
  write_partials8<16>(vals, pr, NB1, red);

  // Phase B: w2 (tanh) + att from LDS
  float at[8]={0,0,0,0,0,0,0,0};
  if (own){
    float m[5];
    #pragma unroll
    for (int k = 0; k < 5; ++k) m[k] = sS[site + (k-2)*25];
    float w2[5] = {0.f,0.f,0.f,0.f,0.f};
    #pragma unroll
    for (int w = 0; w < 5; ++w){
      #pragma unroll
      for (int u = 0; u < 5; ++u){
        int o = w*5 + u;
        float wo = sbw[o];
        #pragma unroll
        for (int k = 0; k < 5; ++k) wo = fmaf(sWw[o*5+k], m[k], wo);
        w2[u] += fast_tanh(wo);
      }
    }
    #pragma unroll
    for (int u = 0; u < 5; ++u){
      float wu = w2[u];
      int base = (site + (u-2)*25)*9;
      #pragma unroll
      for (int r = 0; r < 8; ++r) at[r] = fmaf(wu, sV[base + r], at[r]);
    }
    float* ap = att + (size_t)n*8*TV + gbase;
    #pragma unroll
    for (int r = 0; r < 8; ++r) ap[(size_t)r*TV] = at[r];
  }
  #pragma unroll
  for (int r = 0; r < 8; ++r){
    vals[r]   = own ? at[r] : 0.f;
    vals[8+r] = own ? at[r]*at[r] : 0.f;
  }
  write_partials8<16>(vals, patt, NB1, red);
}

// ==== K2: per-block BN-coef reduce, h in REGISTERS ONLY -> 44 partial moments (no h write)
__global__ __launch_bounds__(256) void k_h(
    const float* __restrict__ att, const float* __restrict__ r0,
    const float* __restrict__ pr, const float* __restrict__ patt,
    const float* __restrict__ g_bn, const float* __restrict__ b_bn,
    const float* __restrict__ g_r, const float* __restrict__ b_r,
    float* __restrict__ ph)
{
  __shared__ float red[44*4];
  __shared__ float sc[32];
  const int tid = threadIdx.x;
  {
    int g = tid >> 3, l8 = tid & 7;       // 32 stats x 8 lanes
    const float* src = (g < 16) ? (pr + g*NB1) : (patt + (g-16)*NB1);
    float sm = 0.f;
    for (int k2 = l8; k2 < NB1; k2 += 8) sm += src[k2];
    sm += __shfl_down(sm, 4, 8); sm += __shfl_down(sm, 2, 8); sm += __shfl_down(sm, 1, 8);
    if (l8 == 0) red[g] = sm;
  }
  __syncthreads();
  if (tid < 8){
    int r = tid;
    float mu_r  = red[r]    / (float)NTV;
    float var_r = red[8+r]  / (float)NTV - mu_r*mu_r;
    float ar_ = g_r[r] * rsqrtf(var_r + EPSF);
    sc[16+r] = ar_; sc[24+r] = b_r[r] - ar_*mu_r;
    float mu_a  = red[16+r] / (float)NTV;
    float var_a = red[24+r] / (float)NTV - mu_a*mu_a;
    float aa = g_bn[r] * rsqrtf(var_a + EPSF);
    sc[r] = aa; sc[8+r] = b_bn[r] - aa*mu_a;
  }
  __syncthreads();

  int p = blockIdx.x*256 + tid;           // float2 site over NTV/2
  int n = p / 1600, j = p - n*1600;
  const float* ap = att + (size_t)n*8*TV + 2*j;
  const float* rp = r0  + (size_t)n*8*TV + 2*j;
  float h0[8], h1[8];
  #pragma unroll
  for (int r = 0; r < 8; ++r){
    float ca = sc[r], cc = sc[8+r], cr = sc[16+r], cd = sc[24+r];
    f2 a = *(const f2*)(ap + (size_t)r*TV);
    f2 rr = *(const f2*)(rp + (size_t)r*TV);
    float z0 = ca*a.x + cc + cr*rr.x + cd;
    float z1 = ca*a.y + cc + cr*rr.y + cd;
    h0[r] = (z0 >= 0.f) ? z0 : 0.1f*z0;
    h1[r] = (z1 >= 0.f) ? z1 : 0.1f*z1;
  }
  float vals[44];
  #pragma unroll
  for (int r = 0; r < 8; ++r) vals[r] = h0[r] + h1[r];
  int cnt = 8;
  #pragma unroll
  for (int r = 0; r < 8; ++r){
    #pragma unroll
    for (int r2 = r; r2 < 8; ++r2) vals[cnt++] = h0[r]*h0[r2] + h1[r]*h1[r2];
  }
  write_partials4<44>(vals, ph, NB2, red);
}

// ==== K3 (NEW, 1 block): reduce ph(44xNB2) + pr/patt(32xNB1) once; fold BN -> fold/bfold/gcoef
__global__ __launch_bounds__(256) void k_fold(
    const float* __restrict__ ph,
    const float* __restrict__ pr, const float* __restrict__ patt,
    const float* __restrict__ g_bn, const float* __restrict__ b_bn,
    const float* __restrict__ g_r, const float* __restrict__ b_r,
    const float* __restrict__ Wo, const float* __restrict__ bo,
    const float* __restrict__ g_o, const float* __restrict__ b_o,
    float* __restrict__ fold, float* __restrict__ bfold, float* __restrict__ gcoef)
{
  __shared__ float hstat[44];
  __shared__ float red[32];
  const int tid = threadIdx.x;
  {
    int lane = tid & 63, wid = tid >> 6;
    for (int s2 = wid; s2 < 44; s2 += 4){
      float sm = 0.f;
      for (int k2 = lane; k2 < NB2; k2 += 64) sm += ph[s2*NB2 + k2];
      #pragma unroll
      for (int o = 32; o > 0; o >>= 1) sm += __shfl_down(sm, o);
      if (lane == 0) hstat[s2] = sm;
    }
  }
  {
    int g = tid >> 3, l8 = tid & 7;       // 32 stats x 8 lanes
    const float* src = (g < 16) ? (pr + g*NB1) : (patt + (g-16)*NB1);
    float sm = 0.f;
    for (int k2 = l8; k2 < NB1; k2 += 8) sm += src[k2];
    sm += __shfl_down(sm, 4, 8); sm += __shfl_down(sm, 2, 8); sm += __shfl_down(sm, 1, 8);
    if (l8 == 0) red[g] = sm;
  }
  __syncthreads();
  if (tid < 8){
    int r = tid;
    float mu_r  = red[r]    / (float)NTV;
    float var_r = red[8+r]  / (float)NTV - mu_r*mu_r;
    float ar_ = g_r[r] * rsqrtf(var_r + EPSF);
    gcoef[16+r] = ar_; gcoef[24+r] = b_r[r] - ar_*mu_r;
    float mu_a  = red[16+r] / (float)NTV;
    float var_a = red[24+r] / (float)NTV - mu_a*mu_a;
    float aa = g_bn[r] * rsqrtf(var_a + EPSF);
    gcoef[r] = aa; gcoef[8+r] = b_bn[r] - aa*mu_a;
  }
  if (tid < 128){
    int o = tid;
    double muh[8];
    #pragma unroll
    for (int r = 0; r < 8; ++r) muh[r] = (double)hstat[r] / (double)NTV;
    double w[8];
    #pragma unroll
    for (int r = 0; r < 8; ++r) w[r] = (double)Wo[o*8+r];
    double bob = (double)bo[o];
    double mu = bob;
    #pragma unroll
    for (int r = 0; r < 8; ++r) mu += w[r]*muh[r];
    double t = 0.0;
    for (int r = 0; r < 8; ++r){
      for (int r2 = 0; r2 < 8; ++r2){
        int lo = (r < r2) ? r : r2, hi = (r < r2) ? r2 : r;
        int idx = 8 + lo*8 - (lo*(lo-1))/2 + (hi - lo);
        t += w[r]*w[r2]*((double)hstat[idx] / (double)NTV);
      }
    }
    double ey2 = t + 2.0*bob*(mu - bob) + bob*bob;
    double var = ey2 - mu*mu;
    double a = (double)g_o[o] / sqrt(var + (double)EPSF);
    #pragma unroll
    for (int r = 0; r < 8; ++r) fold[o*8+r] = (float)(a * w[r]);
    bfold[o] = (float)(a * (bob - mu) + (double)b_o[o]);
  }
}

// ==== K4: out = fold . leaky(bn(att)+bn(r0)) + bfold; h recomputed from att/r0 (L3-resident)
__global__ __launch_bounds__(256) void k_out(
    const float* __restrict__ att, const float* __restrict__ r0,
    const float* __restrict__ fold, const float* __restrict__ bfold,
    const float* __restrict__ gcoef,
    float* __restrict__ out)
{
  __shared__ float sW[1024], sB[128], sc[32];
  const int tid = threadIdx.x;
  for (int i = tid; i < 1024; i += 256) sW[i] = fold[i];
  if (tid < 128) sB[tid] = bfold[tid];
  if (tid < 32)  sc[tid] = gcoef[tid];
  __syncthreads();

  int p  = blockIdx.x*64 + (tid & 63);    // f4-site over NTV/4 (wave = 64 contiguous sites)
  int oq = tid >> 6;                      // o-quarter 0..3 (one wave each)
  int n = p / 800, j = p - n*800;
  const float* ap = att + (size_t)n*8*TV + 4*j;
  const float* rp = r0  + (size_t)n*8*TV + 4*j;
  float hh[8][4];
  #pragma unroll
  for (int r = 0; r < 8; ++r){
    float ca = sc[r], cr = sc[16+r], ccd = sc[8+r] + sc[24+r];
    f4 a  = *(const f4*)(ap + (size_t)r*TV);
    f4 rr = *(const f4*)(rp + (size_t)r*TV);
    #pragma unroll
    for (int e = 0; e < 4; ++e){
      float z = fmaf(ca, a[e], fmaf(cr, rr[e], ccd));
      hh[r][e] = (z >= 0.f) ? z : 0.1f*z;
    }
  }
  const f4* sW4 = (const f4*)sW;
  float* op = out + (size_t)n*128*TV + 4*j;
  #pragma unroll 4
  for (int oo = 0; oo < 32; ++oo){
    int o = oq*32 + oo;
    f4 w0 = sW4[o*2], w1 = sW4[o*2+1];
    float b = sB[o];
    f4 y; y.x = b; y.y = b; y.z = b; y.w = b;
    #pragma unroll
    for (int r = 0; r < 4; ++r){
      #pragma unroll
      for (int e = 0; e < 4; ++e){
        y[e] = fmaf(w0[r], hh[r][e], y[e]);
        y[e] = fmaf(w1[r], hh[4+r][e], y[e]);
      }
    }
    __builtin_nontemporal_store(y, (f4*)(op + (size_t)o*TV));
  }
}

extern "C" void kernel_launch(void* const* d_in, const int* in_sizes, int n_in,
                              void* d_out, int out_size, void* d_ws, size_t ws_size,
                              hipStream_t stream){
  const float* x    = (const float*)d_in[0];
  const float* Wv   = (const float*)d_in[1];
  const float* bv   = (const float*)d_in[2];
  const float* Ww   = (const float*)d_in[3];
  const float* bw   = (const float*)d_in[4];
  const float* g_bn = (const float*)d_in[5];
  const float* b_bn = (const float*)d_in[6];
  const float* Wr   = (const float*)d_in[7];
  const float* br   = (const float*)d_in[8];
  const float* g_r  = (const float*)d_in[9];
  const float* b_r  = (const float*)d_in[10];
  const float* Wo   = (const float*)d_in[11];
  const float* bo   = (const float*)d_in[12];
  const float* g_o  = (const float*)d_in[13];
  const float* b_o  = (const float*)d_in[14];

  float* ws = (float*)d_ws;
  size_t off = 0;
  float* r0    = ws + off; off += 1638400;   // (N,8,T,V)
  float* att   = ws + off; off += 1638400;
  float* pr    = ws + off; off += 16*NB1;
  float* patt  = ws + off; off += 16*NB1;
  float* ph    = ws + off; off += 44*NB2;
  float* fold  = ws + off; off += 1024;
  float* bfold = ws + off; off += 128;
  float* gcoef = ws + off; off += 32;

  k_pw  <<<NB1, 512, 0, stream>>>(x, Wv, bv, Wr, br, Ww, bw, r0, att, pr, patt);
  k_h   <<<NB2, 256, 0, stream>>>(att, r0, pr, patt, g_bn, b_bn, g_r, b_r, ph);
  k_fold<<<1,   256, 0, stream>>>(ph, pr, patt, g_bn, b_bn, g_r, b_r, Wo, bo, g_o, b_o,
                                  fold, bfold, gcoef);
  k_out <<<NB3, 256, 0, stream>>>(att, r0, fold, bfold, gcoef, (float*)d_out);
}

// Round 14
// 233.217 us; speedup vs baseline: 1.0488x; 1.0488x over previous
//
#include <hip/hip_runtime.h>
#include <math.h>

#define TV 3200          // T*V = 128*25
#define NTV 204800       // N*T*V
#define NB1 512          // k_pw blocks: 64 n x 8 q (16-t tile + 2 halo slices each side)
#define NB2 400          // k_h blocks: float2 sites, 400*256 = NTV/2
#define NB3 800          // k_out blocks: (f4-site, o-quarter), 800*256 = NTV/4 * 4
constexpr float EPSF = 1e-5f;

typedef float f2 __attribute__((ext_vector_type(2)));
typedef float f4 __attribute__((ext_vector_type(4)));

// fast tanh: 1 - 2/(e^{2x}+1); exact saturation, ~1e-7 abs err in operating range
__device__ inline float fast_tanh(float x){
  float e = __expf(2.f*x);
  return 1.f - 2.f/(e + 1.f);
}

// 4-wave (256-thread) partial writer; leading sync protects lds scratch reuse
template<int NS>
__device__ inline void write_partials4(float (&vals)[NS], float* __restrict__ outp, int nb, float* lds){
  __syncthreads();
  int lane = threadIdx.x & 63, wid = threadIdx.x >> 6;
  #pragma unroll
  for (int s = 0; s < NS; ++s){
    float v = vals[s];
    #pragma unroll
    for (int o = 32; o > 0; o >>= 1) v += __shfl_down(v, o);
    if (lane == 0) lds[s*4 + wid] = v;
  }
  __syncthreads();
  if ((int)threadIdx.x < NS)
    outp[threadIdx.x*nb + blockIdx.x] = lds[threadIdx.x*4+0] + lds[threadIdx.x*4+1]
                                      + lds[threadIdx.x*4+2] + lds[threadIdx.x*4+3];
}

// ==== K1: fused proj + wat. Block = (n, 16-t tile); v0,s live only in LDS (halo recomputed).
// Weights packed [c][16] -> 4 uniform ds_read_b128 per c-iter.
__global__ __launch_bounds__(256) void k_pw(
    const float* __restrict__ x,
    const float* __restrict__ Wv, const float* __restrict__ bv,
    const float* __restrict__ Wr, const float* __restrict__ br,
    const float* __restrict__ Ww, const float* __restrict__ bw,
    float* __restrict__ r0, float* __restrict__ att,
    float* __restrict__ pr, float* __restrict__ patt)
{
  __shared__ float sV[500*9];         // v0: 20 slices x 25 v, r-dim padded to 9
  __shared__ float sS[500];           // s tile
  __shared__ float sWvr[1024];        // [c][0..7]=Wv[r][c], [c][8..15]=Wr[r][c]
  __shared__ float sWw[125], sbw[25];
  __shared__ float red[16*4];
  const int tid = threadIdx.x;
  const int b = blockIdx.x, n = b >> 3, q = b & 7;
  const int t0 = q*16;
  for (int i2 = tid; i2 < 1024; i2 += 256){
    int c = i2 >> 4, k = i2 & 15;
    sWvr[i2] = (k < 8) ? Wv[k*64 + c] : Wr[(k-8)*64 + c];
  }
  if (tid < 125) sWw[tid] = Ww[tid];
  if (tid < 25)  sbw[tid] = bw[tid];
  __syncthreads();

  const int i = tid;                   // float2 pair index; 0..249 active
  const bool act = (i < 250);
  const int s0 = 2*i, s1 = 2*i + 1;    // site = ls*25+v, ls in [0,20)
  const bool val0 = act && (q > 0 || s0 >= 50) && (q < 7 || s0 < 450);
  const bool val1 = act && (q > 0 || s1 >= 50) && (q < 7 || s1 < 450);
  const bool own  = (i >= 25) && (i < 225);   // both sites in owned slices [2,18)
  const float* xpn = x + (size_t)n*64*TV + (t0*25 - 50);
  const f4* sW4 = (const f4*)sWvr;

  float av0[8]={0,0,0,0,0,0,0,0}, av1[8]={0,0,0,0,0,0,0,0};
  float ar0[8]={0,0,0,0,0,0,0,0}, ar1[8]={0,0,0,0,0,0,0,0};
  float ss0 = 0.f, ss1 = 0.f;
  if (val0 && val1){
    #pragma unroll 8
    for (int c = 0; c < 64; ++c){
      f2 xv = __builtin_nontemporal_load((const f2*)(xpn + (size_t)c*TV + s0));
      ss0 += xv.x; ss1 += xv.y;
      f4 wv0 = sW4[c*4+0], wv1 = sW4[c*4+1];
      f4 wr0 = sW4[c*4+2], wr1 = sW4[c*4+3];
      #pragma unroll
      for (int r = 0; r < 4; ++r){
        av0[r]   = fmaf(wv0[r], xv.x, av0[r]);   av1[r]   = fmaf(wv0[r], xv.y, av1[r]);
        av0[4+r] = fmaf(wv1[r], xv.x, av0[4+r]); av1[4+r] = fmaf(wv1[r], xv.y, av1[4+r]);
        ar0[r]   = fmaf(wr0[r], xv.x, ar0[r]);   ar1[r]   = fmaf(wr0[r], xv.y, ar1[r]);
        ar0[4+r] = fmaf(wr1[r], xv.x, ar0[4+r]); ar1[4+r] = fmaf(wr1[r], xv.y, ar1[4+r]);
      }
    }
  } else if (val0 || val1){
    #pragma unroll 4
    for (int c = 0; c < 64; ++c){
      float x0 = 0.f, x1 = 0.f;
      if (val0) x0 = xpn[(size_t)c*TV + s0];
      if (val1) x1 = xpn[(size_t)c*TV + s1];
      ss0 += x0; ss1 += x1;
      f4 wv0 = sW4[c*4+0], wv1 = sW4[c*4+1];
      f4 wr0 = sW4[c*4+2], wr1 = sW4[c*4+3];
      #pragma unroll
      for (int r = 0; r < 4; ++r){
        av0[r]   = fmaf(wv0[r], x0, av0[r]);   av1[r]   = fmaf(wv0[r], x1, av1[r]);
        av0[4+r] = fmaf(wv1[r], x0, av0[4+r]); av1[4+r] = fmaf(wv1[r], x1, av1[4+r]);
        ar0[r]   = fmaf(wr0[r], x0, ar0[r]);   ar1[r]   = fmaf(wr0[r], x1, ar1[r]);
        ar0[4+r] = fmaf(wr1[r], x0, ar0[4+r]); ar1[4+r] = fmaf(wr1[r], x1, ar1[4+r]);
      }
    }
  }
  if (act){
    sS[s0] = ss0 * 0.015625f;
    sS[s1] = ss1 * 0.015625f;
    #pragma unroll
    for (int r = 0; r < 8; ++r){
      float bvr = bv[r];
      sV[s0*9+r] = val0 ? (av0[r] + bvr) : 0.f;   // zero-pad beyond t-range
      sV[s1*9+r] = val1 ? (av1[r] + bvr) : 0.f;
    }
  }
  const int gbase = t0*25 - 50 + s0;   // global tv offset of site pair (owned => >= 0)
  float vals[16];
  {
    float rr0[8], rr1[8];
    if (own){
      float* rp = r0 + (size_t)n*8*TV + gbase;
      #pragma unroll
      for (int r = 0; r < 8; ++r){
        float brr = br[r];
        rr0[r] = ar0[r] + brr; rr1[r] = ar1[r] + brr;
        f2 rv; rv.x = rr0[r]; rv.y = rr1[r];
        *(f2*)(rp + (size_t)r*TV) = rv;
      }
    }
    #pragma unroll
    for (int r = 0; r < 8; ++r){
      vals[r]   = own ? (rr0[r] + rr1[r]) : 0.f;
      vals[8+r] = own ? (rr0[r]*rr0[r] + rr1[r]*rr1[r]) : 0.f;
    }
  }
  write_partials4<16>(vals, pr, NB1, red);   // internal syncs also publish sV/sS

  // Phase B: w2 (tanh) + att from LDS
  float at0[8]={0,0,0,0,0,0,0,0}, at1[8]={0,0,0,0,0,0,0,0};
  if (own){
    #pragma unroll
    for (int sl = 0; sl < 2; ++sl){
      int s = s0 + sl;
      float m[5];
      #pragma unroll
      for (int k = 0; k < 5; ++k) m[k] = sS[s + (k-2)*25];
      float w2[5] = {0.f,0.f,0.f,0.f,0.f};
      #pragma unroll
      for (int w = 0; w < 5; ++w){
        #pragma unroll
        for (int u = 0; u < 5; ++u){
          int o = w*5 + u;
          float wo = sbw[o];
          #pragma unroll
          for (int k = 0; k < 5; ++k) wo = fmaf(sWw[o*5+k], m[k], wo);
          w2[u] += fast_tanh(wo);
        }
      }
      float* at = sl ? at1 : at0;
      #pragma unroll
      for (int u = 0; u < 5; ++u){
        float wu = w2[u];
        int base = (s + (u-2)*25)*9;
        #pragma unroll
        for (int r = 0; r < 8; ++r) at[r] = fmaf(wu, sV[base + r], at[r]);
      }
    }
    float* ap = att + (size_t)n*8*TV + gbase;
    #pragma unroll
    for (int r = 0; r < 8; ++r){
      f2 av; av.x = at0[r]; av.y = at1[r];
      *(f2*)(ap + (size_t)r*TV) = av;
    }
  }
  #pragma unroll
  for (int r = 0; r < 8; ++r){
    vals[r]   = own ? (at0[r] + at1[r]) : 0.f;
    vals[8+r] = own ? (at0[r]*at0[r] + at1[r]*at1[r]) : 0.f;
  }
  write_partials4<16>(vals, patt, NB1, red);
}

// ==== K2: redundant per-block BN-coef reduce, then h = leaky(bn(att)+bn(r0)); 44 moments
__global__ __launch_bounds__(256) void k_h(
    const float* __restrict__ att, const float* __restrict__ r0,
    const float* __restrict__ pr, const float* __restrict__ patt,
    const float* __restrict__ g_bn, const float* __restrict__ b_bn,
    const float* __restrict__ g_r, const float* __restrict__ b_r,
    float* __restrict__ h, float* __restrict__ ph)
{
  __shared__ float red[44*4];
  __shared__ float sc[32];
  const int tid = threadIdx.x;
  {
    int g = tid >> 3, l8 = tid & 7;       // 32 stats x 8 lanes
    const float* src = (g < 16) ? (pr + g*NB1) : (patt + (g-16)*NB1);
    float sm = 0.f;
    for (int k2 = l8; k2 < NB1; k2 += 8) sm += src[k2];
    sm += __shfl_down(sm, 4, 8); sm += __shfl_down(sm, 2, 8); sm += __shfl_down(sm, 1, 8);
    if (l8 == 0) red[g] = sm;
  }
  __syncthreads();
  if (tid < 8){
    int r = tid;
    float mu_r  = red[r]    / (float)NTV;
    float var_r = red[8+r]  / (float)NTV - mu_r*mu_r;
    float ar_ = g_r[r] * rsqrtf(var_r + EPSF);
    sc[16+r] = ar_; sc[24+r] = b_r[r] - ar_*mu_r;
    float mu_a  = red[16+r] / (float)NTV;
    float var_a = red[24+r] / (float)NTV - mu_a*mu_a;
    float aa = g_bn[r] * rsqrtf(var_a + EPSF);
    sc[r] = aa; sc[8+r] = b_bn[r] - aa*mu_a;
  }
  __syncthreads();

  int p = blockIdx.x*256 + tid;           // float2 site over NTV/2
  int n = p / 1600, j = p - n*1600;
  const float* ap = att + (size_t)n*8*TV + 2*j;
  const float* rp = r0  + (size_t)n*8*TV + 2*j;
  float* hp = h + (size_t)n*8*TV + 2*j;
  float h0[8], h1[8];
  #pragma unroll
  for (int r = 0; r < 8; ++r){
    float ca = sc[r], cc = sc[8+r], cr = sc[16+r], cd = sc[24+r];
    f2 a = *(const f2*)(ap + (size_t)r*TV);
    f2 rr = *(const f2*)(rp + (size_t)r*TV);
    float z0 = ca*a.x + cc + cr*rr.x + cd;
    float z1 = ca*a.y + cc + cr*rr.y + cd;
    h0[r] = (z0 >= 0.f) ? z0 : 0.1f*z0;
    h1[r] = (z1 >= 0.f) ? z1 : 0.1f*z1;
    f2 hh; hh.x = h0[r]; hh.y = h1[r];
    *(f2*)(hp + (size_t)r*TV) = hh;
  }
  float vals[44];
  #pragma unroll
  for (int r = 0; r < 8; ++r) vals[r] = h0[r] + h1[r];
  int cnt = 8;
  #pragma unroll
  for (int r = 0; r < 8; ++r){
    #pragma unroll
    for (int r2 = r; r2 < 8; ++r2) vals[cnt++] = h0[r]*h0[r2] + h1[r]*h1[r2];
  }
  write_partials4<44>(vals, ph, NB2, red);
}

// ==== K3: redundant per-block 44-stat reduce + BN fold, then out.
__global__ __launch_bounds__(256) void k_out(
    const float* __restrict__ h, const float* __restrict__ ph,
    const float* __restrict__ Wo, const float* __restrict__ bo,
    const float* __restrict__ g_o, const float* __restrict__ b_o,
    float* __restrict__ out)
{
  __shared__ float hstat[44];
  __shared__ float sW[1024], sB[128];
  const int tid = threadIdx.x;
  {
    int lane = tid & 63, wid = tid >> 6;
    for (int s2 = wid; s2 < 44; s2 += 4){
      float sm = 0.f;
      for (int k2 = lane; k2 < NB2; k2 += 64) sm += ph[s2*NB2 + k2];
      #pragma unroll
      for (int o = 32; o > 0; o >>= 1) sm += __shfl_down(sm, o);
      if (lane == 0) hstat[s2] = sm;
    }
  }
  __syncthreads();
  if (tid < 128){
    int o = tid;     // one output channel each
    double muh[8];
    #pragma unroll
    for (int r = 0; r < 8; ++r) muh[r] = (double)hstat[r] / (double)NTV;
    double w[8];
    #pragma unroll
    for (int r = 0; r < 8; ++r) w[r] = (double)Wo[o*8+r];
    double bob = (double)bo[o];
    double mu = bob;
    #pragma unroll
    for (int r = 0; r < 8; ++r) mu += w[r]*muh[r];
    double t = 0.0;
    for (int r = 0; r < 8; ++r){
      for (int r2 = 0; r2 < 8; ++r2){
        int lo = (r < r2) ? r : r2, hi = (r < r2) ? r2 : r;
        int idx = 8 + lo*8 - (lo*(lo-1))/2 + (hi - lo);
        t += w[r]*w[r2]*((double)hstat[idx] / (double)NTV);
      }
    }
    double ey2 = t + 2.0*bob*(mu - bob) + bob*bob;
    double var = ey2 - mu*mu;
    double a = (double)g_o[o] / sqrt(var + (double)EPSF);
    #pragma unroll
    for (int r = 0; r < 8; ++r) sW[o*8+r] = (float)(a * w[r]);
    sB[o] = (float)(a * (bob - mu) + (double)b_o[o]);
  }
  __syncthreads();

  int p  = blockIdx.x*64 + (tid & 63);    // f4-site over NTV/4 (wave = 64 contiguous sites)
  int oq = tid >> 6;                      // o-quarter 0..3 (one wave each)
  int n = p / 800, j = p - n*800;
  const float* hp = h + (size_t)n*8*TV + 4*j;
  float hh[8][4];
  #pragma unroll
  for (int r = 0; r < 8; ++r){
    f4 v = *(const f4*)(hp + (size_t)r*TV);
    hh[r][0] = v[0]; hh[r][1] = v[1]; hh[r][2] = v[2]; hh[r][3] = v[3];
  }
  const f4* sW4 = (const f4*)sW;
  float* op = out + (size_t)n*128*TV + 4*j;
  #pragma unroll 4
  for (int oo = 0; oo < 32; ++oo){
    int o = oq*32 + oo;
    f4 w0 = sW4[o*2], w1 = sW4[o*2+1];
    float b = sB[o];
    f4 y; y.x = b; y.y = b; y.z = b; y.w = b;
    #pragma unroll
    for (int r = 0; r < 4; ++r){
      #pragma unroll
      for (int e = 0; e < 4; ++e){
        y[e] = fmaf(w0[r], hh[r][e], y[e]);
        y[e] = fmaf(w1[r], hh[4+r][e], y[e]);
      }
    }
    __builtin_nontemporal_store(y, (f4*)(op + (size_t)o*TV));
  }
}

extern "C" void kernel_launch(void* const* d_in, const int* in_sizes, int n_in,
                              void* d_out, int out_size, void* d_ws, size_t ws_size,
                              hipStream_t stream){
  const float* x    = (const float*)d_in[0];
  const float* Wv   = (const float*)d_in[1];
  const float* bv   = (const float*)d_in[2];
  const float* Ww   = (const float*)d_in[3];
  const float* bw   = (const float*)d_in[4];
  const float* g_bn = (const float*)d_in[5];
  const float* b_bn = (const float*)d_in[6];
  const float* Wr   = (const float*)d_in[7];
  const float* br   = (const float*)d_in[8];
  const float* g_r  = (const float*)d_in[9];
  const float* b_r  = (const float*)d_in[10];
  const float* Wo   = (const float*)d_in[11];
  const float* bo   = (const float*)d_in[12];
  const float* g_o  = (const float*)d_in[13];
  const float* b_o  = (const float*)d_in[14];

  float* ws = (float*)d_ws;
  size_t off = 0;
  float* r0   = ws + off; off += 1638400;   // (N,8,T,V)
  float* att  = ws + off; off += 1638400;
  float* hbuf = ws + off; off += 1638400;
  float* pr   = ws + off; off += 16*NB1;
  float* patt = ws + off; off += 16*NB1;
  float* ph   = ws + off; off += 44*NB2;

  k_pw <<<NB1, 256, 0, stream>>>(x, Wv, bv, Wr, br, Ww, bw, r0, att, pr, patt);
  k_h  <<<NB2, 256, 0, stream>>>(att, r0, pr, patt, g_bn, b_bn, g_r, b_r, hbuf, ph);
  k_out<<<NB3, 256, 0, stream>>>(hbuf, ph, Wo, bo, g_o, b_o, (float*)d_out);
}